// Round 4
// baseline (166.578 us; speedup 1.0000x reference)
//
#include <hip/hip_runtime.h>

// y[b, c, h, w] = x[b, h, w] * kernels[c, h, w]
// B=128, C=32, H=W=224 -> HW = 50176 floats = 12544 float4 per slab.
// HBM-write-bound (822 MB out, 32 MB in). Register-tile 8b x 8c per thread
// (16 loads per 64 stores -> 206 MB instr-level reads) + XCD-keyed tile
// mapping so each XCD's k-panel (1.6 MB) stays L2-resident. Nontemporal
// stores keep the write stream from evicting the read working set.

#define HW    50176
#define HW4   12544          // HW / 4 (float4 units)
#define CC    32
#define BB    128
#define NB    8              // b's per thread
#define NC    8              // c's per thread
// ty = btile*4 + ctile; btiles = 16, ctiles = 4; ty in [0,64)
// gridDim.x = 64 == 0 mod 8 -> XCD ~= ty % 8 = (btile*4 + ctile) % 8:
// each XCD handles ONE ctile (k panel 8*200KB = 1.6MB, L2-resident).

typedef float f32x4 __attribute__((ext_vector_type(4)));

__global__ __launch_bounds__(256) void involution_mul_kernel(
    const float* __restrict__ x,
    const float* __restrict__ k,
    float* __restrict__ out)
{
    const int i  = blockIdx.y * 256 + threadIdx.x;   // float4 idx in [0, HW4)
    const int ty = blockIdx.x;                       // tile id, XCD = ty % 8
    const int b0 = (ty >> 2) * NB;                   // b tile base
    const int c0 = (ty & 3) * NC;                    // c tile base

    const f32x4* xp = reinterpret_cast<const f32x4*>(x) + (size_t)b0 * HW4 + i;
    const f32x4* kp = reinterpret_cast<const f32x4*>(k) + (size_t)c0 * HW4 + i;

    f32x4 xv[NB], kv[NC];
#pragma unroll
    for (int ib = 0; ib < NB; ++ib) xv[ib] = xp[(size_t)ib * HW4];
#pragma unroll
    for (int ic = 0; ic < NC; ++ic) kv[ic] = kp[(size_t)ic * HW4];

    f32x4* op = reinterpret_cast<f32x4*>(out) + ((size_t)b0 * CC + c0) * HW4 + i;
#pragma unroll
    for (int ib = 0; ib < NB; ++ib) {
#pragma unroll
        for (int ic = 0; ic < NC; ++ic) {
            f32x4 o = xv[ib] * kv[ic];
            __builtin_nontemporal_store(o, op + ((size_t)ib * CC + ic) * HW4);
        }
    }
}

extern "C" void kernel_launch(void* const* d_in, const int* in_sizes, int n_in,
                              void* d_out, int out_size, void* d_ws, size_t ws_size,
                              hipStream_t stream) {
    const float* x = (const float*)d_in[0];   // [128, 224, 224]
    const float* k = (const float*)d_in[1];   // [32, 224, 224]
    float* out = (float*)d_out;               // [128, 32, 224, 224]

    dim3 grid((BB / NB) * (CC / NC), HW4 / 256);   // (64, 49)
    involution_mul_kernel<<<grid, 256, 0, stream>>>(x, k, out);
}

// Round 5
// 164.571 us; speedup vs baseline: 1.0122x; 1.0122x over previous
//
#include <hip/hip_runtime.h>

// y[b, c, h, w] = x[b, h, w] * kernels[c, h, w]
// B=128, C=32, H=W=224 -> HW = 50176 floats = 12544 float4 per slab.
// HBM-write-bound (822 MB out, 32 MB in). R3 structure (4b x 4c per thread,
// 12544 blocks) + XCD-keyed tile mapping: tile in blockIdx.x, gridDim.x=256
// == 0 mod 8, ctile = bx & 7 -> each XCD sees ONE ctile, its k panel
// (4 x 200 KB = 800 KB) stays L2-resident. NT stores keep L2 clean.

#define HW    50176
#define HW4   12544          // HW / 4 (float4 units)
#define CC    32
#define BB    128
#define NB    4              // b's per thread
#define NC    4              // c's per thread

typedef float f32x4 __attribute__((ext_vector_type(4)));

__global__ __launch_bounds__(256) void involution_mul_kernel(
    const float* __restrict__ x,
    const float* __restrict__ k,
    float* __restrict__ out)
{
    const int tile = blockIdx.x;                     // 256 tiles, XCD ~= tile % 8
    const int b0 = (tile >> 3) * NB;                 // btile = tile/8  (32 values)
    const int c0 = (tile & 7) * NC;                  // ctile = tile%8 -> pinned per XCD
    const int i  = blockIdx.y * 256 + threadIdx.x;   // float4 idx in [0, HW4)

    const f32x4* xp = reinterpret_cast<const f32x4*>(x) + (size_t)b0 * HW4 + i;
    const f32x4* kp = reinterpret_cast<const f32x4*>(k) + (size_t)c0 * HW4 + i;

    f32x4 xv[NB], kv[NC];
#pragma unroll
    for (int ib = 0; ib < NB; ++ib) xv[ib] = xp[(size_t)ib * HW4];
#pragma unroll
    for (int ic = 0; ic < NC; ++ic) kv[ic] = kp[(size_t)ic * HW4];

    f32x4* op = reinterpret_cast<f32x4*>(out) + ((size_t)b0 * CC + c0) * HW4 + i;
#pragma unroll
    for (int ib = 0; ib < NB; ++ib) {
#pragma unroll
        for (int ic = 0; ic < NC; ++ic) {
            f32x4 o = xv[ib] * kv[ic];
            __builtin_nontemporal_store(o, op + ((size_t)ib * CC + ic) * HW4);
        }
    }
}

extern "C" void kernel_launch(void* const* d_in, const int* in_sizes, int n_in,
                              void* d_out, int out_size, void* d_ws, size_t ws_size,
                              hipStream_t stream) {
    const float* x = (const float*)d_in[0];   // [128, 224, 224]
    const float* k = (const float*)d_in[1];   // [32, 224, 224]
    float* out = (float*)d_out;               // [128, 32, 224, 224]

    dim3 grid((BB / NB) * (CC / NC), HW4 / 256);   // (256, 49)
    involution_mul_kernel<<<grid, 256, 0, stream>>>(x, k, out);
}